// Round 7
// baseline (43.501 us; speedup 1.0000x reference)
//
#include <hip/hip_runtime.h>
#include <math.h>

// Problem constants (from setup_inputs)
#define D 1024
#define M 8192
#define N 16384
#define EPS 1e-8

#define ROWS 16                      // rows per streaming block
#define IN_BLOCKS (N / ROWS)         // 1024
#define EM_BLOCKS (M / ROWS)         // 512
#define GRID1 (IN_BLOCKS + EM_BLOCKS) // 1536  (6 blocks/CU, 24 waves/CU)
#define RED_BLOCKS 64                // reduce kernel: 16 columns per block

// ws layout:
//   pSign [IN_BLOCKS][D] signed char  (1 MB)
//   pS    [EM_BLOCKS][D] f32          (2 MB)
//   pQ    [EM_BLOCKS][D] f32          (2 MB)
//   blockRes [RED_BLOCKS] f64
//   counter  int   (zeroed by K1 — NO memset node, they cost 40 us)

__global__ __launch_bounds__(256) void stream_kernel(const float* __restrict__ input,
                                                     const float* __restrict__ embed,
                                                     signed char* __restrict__ pSign,
                                                     float* __restrict__ pS,
                                                     float* __restrict__ pQ,
                                                     int* __restrict__ counter) {
    const int b = blockIdx.x;
    const int t = threadIdx.x;
    const int col = t * 4;

    if (b == 0 && t == 0) *counter = 0;  // visible to K2 via kernel-boundary ordering

    if (b < IN_BLOCKS) {
        const float4* src = reinterpret_cast<const float4*>(input + (size_t)b * ROWS * D + col);
        int s0 = 0, s1 = 0, s2 = 0, s3 = 0;
#pragma unroll
        for (int r = 0; r < ROWS; ++r) {
            float4 v = src[(size_t)r * (D / 4)];
            s0 += (v.x > 0.f) - (v.x < 0.f);
            s1 += (v.y > 0.f) - (v.y < 0.f);
            s2 += (v.z > 0.f) - (v.z < 0.f);
            s3 += (v.w > 0.f) - (v.w < 0.f);
        }
        char4 packed;
        packed.x = (signed char)s0; packed.y = (signed char)s1;
        packed.z = (signed char)s2; packed.w = (signed char)s3;
        *reinterpret_cast<char4*>(pSign + (size_t)b * D + col) = packed;
    } else {
        const int e = b - IN_BLOCKS;
        const float4* src = reinterpret_cast<const float4*>(embed + (size_t)e * ROWS * D + col);
        float4 s = make_float4(0.f, 0.f, 0.f, 0.f);
        float4 q = make_float4(0.f, 0.f, 0.f, 0.f);
#pragma unroll
        for (int r = 0; r < ROWS; ++r) {
            float4 v = src[(size_t)r * (D / 4)];
            s.x += v.x; s.y += v.y; s.z += v.z; s.w += v.w;
            q.x += v.x * v.x; q.y += v.y * v.y; q.z += v.z * v.z; q.w += v.w * v.w;
        }
        *reinterpret_cast<float4*>(pS + (size_t)e * D + col) = s;
        *reinterpret_cast<float4*>(pQ + (size_t)e * D + col) = q;
    }
}

// K2: 64 blocks, 16 columns each; last block (ticket) folds the 64 partials.
__global__ __launch_bounds__(256) void reduce_kernel(const signed char* __restrict__ pSign,
                                                     const float* __restrict__ pS,
                                                     const float* __restrict__ pQ,
                                                     double* __restrict__ blockRes,
                                                     int* __restrict__ counter,
                                                     float* __restrict__ out) {
    const int t = threadIdx.x;
    const int g = t >> 4;        // 0..15 stripe over source blocks
    const int c = t & 15;        // 0..15 column within this block's slice
    const int d = blockIdx.x * 16 + c;

    int sgn = 0;
    for (int bb = g; bb < IN_BLOCKS; bb += 16)
        sgn += (int)pSign[(size_t)bb * D + d];
    double se = 0.0, qq = 0.0;
    for (int bb = g; bb < EM_BLOCKS; bb += 16) {
        se += (double)pS[(size_t)bb * D + d];
        qq += (double)pQ[(size_t)bb * D + d];
    }

    // fold the 4 stripes per wave (lanes differing by 16, 32)
    sgn += __shfl_xor(sgn, 16); sgn += __shfl_xor(sgn, 32);
    se  += __shfl_xor(se, 16);  se  += __shfl_xor(se, 32);
    qq  += __shfl_xor(qq, 16);  qq  += __shfl_xor(qq, 32);

    __shared__ double ls[3][4][16];
    __shared__ double contrib[16];
    const int wid = t >> 6;
    const int lane = t & 63;
    if (lane < 16) { ls[0][wid][lane] = (double)sgn; ls[1][wid][lane] = se; ls[2][wid][lane] = qq; }
    __syncthreads();

    if (t < 16) {
        double S = ls[0][0][t] + ls[0][1][t] + ls[0][2][t] + ls[0][3][t];
        double E = ls[1][0][t] + ls[1][1][t] + ls[1][2][t] + ls[1][3][t];
        double Q = ls[2][0][t] + ls[2][1][t] + ls[2][2][t] + ls[2][3][t];
        double n2 = sqrt(Q);
        // per-column term sum: (s_e / (sqrt(M)*max(n2,eps))) * signcount
        contrib[t] = (E / (90.50966799187809 * fmax(n2, EPS))) * S;
    }
    __syncthreads();
    if (t == 0) {
        double acc = 0.0;
        for (int i = 0; i < 16; ++i) acc += contrib[i];   // fixed order
        __hip_atomic_store(&blockRes[blockIdx.x], acc, __ATOMIC_RELEASE,
                           __HIP_MEMORY_SCOPE_AGENT);
    }

    // ---- ticket: last finishing block folds the 64 results ----
    __shared__ int isLast;
    if (t == 0) {
        int old = __hip_atomic_fetch_add(counter, 1, __ATOMIC_ACQ_REL,
                                         __HIP_MEMORY_SCOPE_AGENT);
        isLast = (old == RED_BLOCKS - 1);
    }
    __syncthreads();
    if (isLast && t < 64) {
        double a = __hip_atomic_load(&blockRes[t], __ATOMIC_ACQUIRE,
                                     __HIP_MEMORY_SCOPE_AGENT);
        for (int off = 32; off > 0; off >>= 1) a += __shfl_down(a, off);
        if (t == 0) out[0] = (float)a;
    }
}

extern "C" void kernel_launch(void* const* d_in, const int* in_sizes, int n_in,
                              void* d_out, int out_size, void* d_ws, size_t ws_size,
                              hipStream_t stream) {
    const float* input = (const float*)d_in[0];   // [N, D]
    const float* embed = (const float*)d_in[1];   // [M, D]
    float* out = (float*)d_out;

    char* ws = (char*)d_ws;
    signed char* pSign = (signed char*)ws;                              // 1 MB
    float* pS = (float*)(ws + (size_t)IN_BLOCKS * D);                   // 2 MB
    float* pQ = pS + (size_t)EM_BLOCKS * D;                             // 2 MB
    double* blockRes = (double*)(pQ + (size_t)EM_BLOCKS * D);           // 64 f64
    int* counter = (int*)(blockRes + RED_BLOCKS);

    stream_kernel<<<GRID1, 256, 0, stream>>>(input, embed, pSign, pS, pQ, counter);
    reduce_kernel<<<RED_BLOCKS, 256, 0, stream>>>(pSign, pS, pQ, blockRes, counter, out);
}